// Round 3
// baseline (120.254 us; speedup 1.0000x reference)
//
#include <hip/hip_runtime.h>
#include <math.h>

#define DIM 4096
#define NQ 12
#define NLAYERS 5
#define TPB 256
#define NGATES 72   // 6 layers x 12 qubits

__device__ __forceinline__ float2 cmul(float2 a, float2 b) {
    return make_float2(a.x * b.x - a.y * b.y, a.x * b.y + a.y * b.x);
}
__device__ __forceinline__ float2 cadd(float2 a, float2 b) {
    return make_float2(a.x + b.x, a.y + b.y);
}
__device__ __forceinline__ float2 cmad(float2 a, float2 s, float2 acc) {
    acc.x += a.x * s.x - a.y * s.y;
    acc.y += a.x * s.y + a.y * s.x;
    return acc;
}
__device__ __forceinline__ void mat2mul(const float2 A[4], const float2 B[4], float2 C[4]) {
    C[0] = cadd(cmul(A[0], B[0]), cmul(A[1], B[2]));
    C[1] = cadd(cmul(A[0], B[1]), cmul(A[1], B[3]));
    C[2] = cadd(cmul(A[2], B[0]), cmul(A[3], B[2]));
    C[3] = cadd(cmul(A[2], B[1]), cmul(A[3], B[3]));
}

// Gate on register-local bit LB (global bit LB, qubit 11-LB).
template<int LB>
__device__ __forceinline__ void gate_on_bit(float2 (&r)[16], const float2* __restrict__ g) {
    const float2 u00 = g[0], u01 = g[1], u10 = g[2], u11 = g[3];
    constexpr int m = 1 << LB;
    #pragma unroll
    for (int j = 0; j < 16; ++j) {
        if (!(j & m)) {
            const float2 s0 = r[j], s1 = r[j + m];
            float2 n0, n1;
            n0.x = u00.x * s0.x - u00.y * s0.y + u01.x * s1.x - u01.y * s1.y;
            n0.y = u00.x * s0.y + u00.y * s0.x + u01.x * s1.y + u01.y * s1.x;
            n1.x = u10.x * s0.x - u10.y * s0.y + u11.x * s1.x - u11.y * s1.y;
            n1.y = u10.x * s0.y + u10.y * s0.x + u11.x * s1.y + u11.y * s1.x;
            r[j] = n0; r[j + m] = n1;
        }
    }
}

// Gate on lane bit (global bit 4+log2(MASK)) via shfl_xor: zero barriers.
// Lane with bit==0 computes row0: n = u00*own + u01*partner.
// Lane with bit==1 computes row1: n = u11*own + u10*partner.
template<int MASK>
__device__ __forceinline__ void lane_gate(float2 (&r)[16], const float2* __restrict__ g) {
    const bool hi = (threadIdx.x & MASK) != 0;
    const float2 g0 = g[0], g1 = g[1], g2 = g[2], g3 = g[3];
    const float2 ua = hi ? g3 : g0;   // coeff on own amplitude
    const float2 ub = hi ? g2 : g1;   // coeff on partner amplitude
    #pragma unroll
    for (int j = 0; j < 16; ++j) {
        float2 p;
        p.x = __shfl_xor(r[j].x, MASK, 64);
        p.y = __shfl_xor(r[j].y, MASK, 64);
        const float2 o = r[j];
        float2 n;
        n.x = ua.x * o.x - ua.y * o.y + ub.x * p.x - ub.y * p.y;
        n.y = ua.x * o.y + ua.y * o.x + ub.x * p.y + ub.y * p.x;
        r[j] = n;
    }
}

__global__ __launch_bounds__(TPB) void qsim_kernel(const float* __restrict__ x,
                                                   const float* __restrict__ w,
                                                   float* __restrict__ out) {
    // amplitude i lives at slot(i) = i ^ (((i>>4)&7)<<1)  (bits 10,11 untouched)
    __shared__ __align__(16) float2 st[DIM];   // 32 KB
    __shared__ float2 gmat[NGATES * 4];        // 2.25 KB
    __shared__ float red[4];

    const int tid = threadIdx.x;
    const int b = blockIdx.x;
    const int w1 = (tid >> 7) & 1;   // state bit 11 (qubit 0)
    const int w0 = (tid >> 6) & 1;   // state bit 10 (qubit 1)

    // ---- build fused per-qubit gate matrices (threads 0..71) ----
    if (tid < NGATES) {
        const int l = tid / NQ;
        const int q = tid % NQ;
        const float* pp = w + (l < NLAYERS ? l * (3 * NQ) : NLAYERS * (3 * NQ)) + q * 3;
        float s0, c0, s1, c1, s2, c2;
        sincosf(0.5f * pp[0], &s0, &c0);
        sincosf(0.5f * pp[1], &s1, &c1);
        sincosf(0.5f * pp[2], &s2, &c2);
        float2 U[4], M[4];
        if (l < NLAYERS) {
            float2 RX[4] = { {c0, 0.f}, {0.f, -s0}, {0.f, -s0}, {c0, 0.f} };
            float2 RY[4] = { {c1, 0.f}, {-s1, 0.f}, {s1, 0.f}, {c1, 0.f} };
            float2 RZ[4] = { {c2, -s2}, {0.f, 0.f}, {0.f, 0.f}, {c2, s2} };
            mat2mul(RY, RX, M);
            mat2mul(RZ, M, U);
        } else {
            float2 RY0[4] = { {c0, 0.f}, {-s0, 0.f}, {s0, 0.f}, {c0, 0.f} };
            float2 RZ1[4] = { {c1, -s1}, {0.f, 0.f}, {0.f, 0.f}, {c1, s1} };
            float2 RY2[4] = { {c2, 0.f}, {-s2, 0.f}, {s2, 0.f}, {c2, 0.f} };
            mat2mul(RZ1, RY0, M);
            mat2mul(RY2, M, U);
        }
        gmat[tid * 4 + 0] = U[0];
        gmat[tid * 4 + 1] = U[1];
        gmat[tid * 4 + 2] = U[2];
        gmat[tid * 4 + 3] = U[3];
    }

    // ---- load x (layout i = (tid<<4)|j), sum of squares ----
    const float* xb = x + (size_t)b * DIM;
    float2 r[16];
    float ss = 0.f;
    {
        const float4* xv = reinterpret_cast<const float4*>(xb + 16 * tid);
        #pragma unroll
        for (int k = 0; k < 4; ++k) {
            float4 v = xv[k];
            r[k * 4 + 0] = make_float2(v.x, 0.f);
            r[k * 4 + 1] = make_float2(v.y, 0.f);
            r[k * 4 + 2] = make_float2(v.z, 0.f);
            r[k * 4 + 3] = make_float2(v.w, 0.f);
            ss += v.x * v.x + v.y * v.y + v.z * v.z + v.w * v.w;
        }
    }
    #pragma unroll
    for (int off = 32; off > 0; off >>= 1) ss += __shfl_down(ss, off, 64);
    if ((tid & 63) == 0) red[tid >> 6] = ss;
    __syncthreads();   // covers gmat + red

    const float total = red[0] + red[1] + red[2] + red[3];
    const float inv = 1.0f / sqrtf(sqrtf(total) + 1e-12f);
    #pragma unroll
    for (int j = 0; j < 16; ++j) { r[j].x *= inv; }

    const int swz = (tid & 7) << 1;   // local-slot xor for this thread's writes

    // ---- circuit ----
    for (int l = 0; l < NLAYERS + 1; ++l) {
        const int goff = 12 * l;

        // qubits 11..8 on local bits 0..3 (register-only)
        gate_on_bit<0>(r, gmat + 4 * (goff + 11));
        gate_on_bit<1>(r, gmat + 4 * (goff + 10));
        gate_on_bit<2>(r, gmat + 4 * (goff + 9));
        gate_on_bit<3>(r, gmat + 4 * (goff + 8));

        // qubits 7..2 on lane bits 4..9 (shfl_xor, no barriers)
        lane_gate<1>(r, gmat + 4 * (goff + 7));
        lane_gate<2>(r, gmat + 4 * (goff + 6));
        lane_gate<4>(r, gmat + 4 * (goff + 5));
        lane_gate<8>(r, gmat + 4 * (goff + 4));
        lane_gate<16>(r, gmat + 4 * (goff + 3));
        lane_gate<32>(r, gmat + 4 * (goff + 2));

        // qubits 0,1 on wave bits 11,10 : one LDS pass, 4x4 complex matvec.
        // For l < NLAYERS the ring-of-CNOT permutation is fused into the read.
        const float2* G11 = gmat + 4 * (goff + 0);   // qubit 0 -> bit 11
        const float2* G10 = gmat + 4 * (goff + 1);   // qubit 1 -> bit 10

        // write all regs (b128, swizzled, conflict-free)
        #pragma unroll
        for (int k = 0; k < 8; ++k) {
            const int j = 2 * k;
            const int slot = (tid << 4) | (j ^ swz);
            *reinterpret_cast<float4*>(&st[slot]) =
                make_float4(r[j].x, r[j].y, r[j + 1].x, r[j + 1].y);
        }
        __syncthreads();

        if (l < NLAYERS) {
            // rows for even/odd j (y11 = w1^p, y10 = w0^w1^p, p = j&1)
            const int aE11 = w1, aE10 = w0 ^ w1;
            const int aO11 = w1 ^ 1, aO10 = aE10 ^ 1;
            float2 rowE[4], rowO[4];
            #pragma unroll
            for (int c = 0; c < 4; ++c) {
                rowE[c] = cmul(G11[aE11 * 2 + (c >> 1)], G10[aE10 * 2 + (c & 1)]);
                rowO[c] = cmul(G11[aO11 * 2 + (c >> 1)], G10[aO10 * 2 + (c & 1)]);
            }
            #pragma unroll
            for (int j = 0; j < 16; ++j) {
                const int i = (tid << 4) | j;
                const int yl = (i ^ (i >> 1)) & 0x3FF;
                const int slot = yl ^ (((yl >> 4) & 7) << 1);
                const float2 s0 = st[slot];
                const float2 s1 = st[slot + 1024];
                const float2 s2 = st[slot + 2048];
                const float2 s3 = st[slot + 3072];
                float2 n = make_float2(0.f, 0.f);
                if (j & 1) {
                    n = cmad(rowO[0], s0, n); n = cmad(rowO[1], s1, n);
                    n = cmad(rowO[2], s2, n); n = cmad(rowO[3], s3, n);
                } else {
                    n = cmad(rowE[0], s0, n); n = cmad(rowE[1], s1, n);
                    n = cmad(rowE[2], s2, n); n = cmad(rowE[3], s3, n);
                }
                r[j] = n;
            }
        } else {
            // final layer: no CNOT, row fixed by this thread's wave bits
            float2 rowF[4];
            #pragma unroll
            for (int c = 0; c < 4; ++c) {
                rowF[c] = cmul(G11[w1 * 2 + (c >> 1)], G10[w0 * 2 + (c & 1)]);
            }
            #pragma unroll
            for (int j = 0; j < 16; ++j) {
                const int i = (tid << 4) | j;
                const int il = i & 0x3FF;
                const int slot = il ^ (((il >> 4) & 7) << 1);
                const float2 s0 = st[slot];
                const float2 s1 = st[slot + 1024];
                const float2 s2 = st[slot + 2048];
                const float2 s3 = st[slot + 3072];
                float2 n = make_float2(0.f, 0.f);
                n = cmad(rowF[0], s0, n); n = cmad(rowF[1], s1, n);
                n = cmad(rowF[2], s2, n); n = cmad(rowF[3], s3, n);
                r[j] = n;
            }
        }
        __syncthreads();
    }

    // ---- store real parts: thread owns 16 consecutive amps -> 4x float4 ----
    float* ob = out + (size_t)b * DIM + 16 * tid;
    #pragma unroll
    for (int k = 0; k < 4; ++k) {
        reinterpret_cast<float4*>(ob)[k] =
            make_float4(r[4 * k + 0].x, r[4 * k + 1].x, r[4 * k + 2].x, r[4 * k + 3].x);
    }
}

extern "C" void kernel_launch(void* const* d_in, const int* in_sizes, int n_in,
                              void* d_out, int out_size, void* d_ws, size_t ws_size,
                              hipStream_t stream) {
    const float* x = (const float*)d_in[0];      // [1024, 4096] f32
    const float* w = (const float*)d_in[1];      // [216] f32
    float* out = (float*)d_out;                  // [1024, 4096] f32
    qsim_kernel<<<dim3(1024), dim3(TPB), 0, stream>>>(x, w, out);
}

// Round 4
// 69.729 us; speedup vs baseline: 1.7246x; 1.7246x over previous
//
#include <hip/hip_runtime.h>
#include <math.h>

#define DIM 4096
#define NQ 12
#define NLAYERS 5
#define TPB 256
#define NGATES 72   // 6 layers x 12 qubits

typedef float v2f __attribute__((ext_vector_type(2)));
typedef float v4f __attribute__((ext_vector_type(4)));

// ---- scalar complex helpers (setup only) ----
__device__ __forceinline__ float2 cmul(float2 a, float2 b) {
    return make_float2(a.x * b.x - a.y * b.y, a.x * b.y + a.y * b.x);
}
__device__ __forceinline__ float2 cadd(float2 a, float2 b) {
    return make_float2(a.x + b.x, a.y + b.y);
}
__device__ __forceinline__ void mat2mul(const float2 A[4], const float2 B[4], float2 C[4]) {
    C[0] = cadd(cmul(A[0], B[0]), cmul(A[1], B[2]));
    C[1] = cadd(cmul(A[0], B[1]), cmul(A[1], B[3]));
    C[2] = cadd(cmul(A[2], B[0]), cmul(A[3], B[2]));
    C[3] = cadd(cmul(A[2], B[1]), cmul(A[3], B[3]));
}

// ---- packed complex butterfly: (a0,a1) <- U * (a0,a1) ----
// A = (u00.re,u00.im,u01.re,u01.im), B = (u10.re,u10.im,u11.re,u11.im)
__device__ __forceinline__ void bfly(v2f& a0, v2f& a1, v4f A, v4f B) {
    const v2f t0 = {-a0.y, a0.x};
    const v2f t1 = {-a1.y, a1.x};
    v2f n0 = A.x * a0;
    n0 += A.y * t0;
    n0 += A.z * a1;
    n0 += A.w * t1;
    v2f n1 = B.x * a0;
    n1 += B.y * t0;
    n1 += B.z * a1;
    n1 += B.w * t1;
    a0 = n0; a1 = n1;
}

// Gate on register-local bit LB (global bit LB, qubit 11-LB).
template<int LB>
__device__ __forceinline__ void gate_on_bit(v2f (&r)[16], const v2f* __restrict__ g) {
    const v4f A = *reinterpret_cast<const v4f*>(g);
    const v4f B = *reinterpret_cast<const v4f*>(g + 2);
    constexpr int m = 1 << LB;
    #pragma unroll
    for (int j = 0; j < 16; ++j) {
        if (!(j & m)) bfly(r[j], r[j + m], A, B);
    }
}

// Phase with global bit base BETA (0=C,4=B,8=A): local bit lb -> global bit
// b = BETA+lb -> qubit q = 11-b -> gate index goff + (11-BETA-lb).
template<int BETA>
__device__ __forceinline__ void apply_phase(v2f (&r)[16], const v2f* __restrict__ gm, int goff) {
    gate_on_bit<0>(r, gm + 4 * (goff + 11 - BETA - 0));
    gate_on_bit<1>(r, gm + 4 * (goff + 11 - BETA - 1));
    gate_on_bit<2>(r, gm + 4 * (goff + 11 - BETA - 2));
    gate_on_bit<3>(r, gm + 4 * (goff + 11 - BETA - 3));
}

__global__ __launch_bounds__(TPB) void qsim_kernel(const float* __restrict__ x,
                                                   const float* __restrict__ w,
                                                   float* __restrict__ out) {
    // XOR bank-swizzled state buffer: amplitude i lives at slot S(i) = i ^ ((i>>3)&14)
    __shared__ __align__(16) v2f st[DIM];      // 32 KB
    __shared__ __align__(16) v2f gmat[NGATES * 4];  // 2.25 KB
    __shared__ float red[4];

    const int tid = threadIdx.x;
    const int b = blockIdx.x;

    // ---- build fused per-qubit gate matrices (threads 0..71) ----
    if (tid < NGATES) {
        const int l = tid / NQ;
        const int q = tid % NQ;
        const float* pp = w + (l < NLAYERS ? l * (3 * NQ) : NLAYERS * (3 * NQ)) + q * 3;
        float s0, c0, s1, c1, s2, c2;
        sincosf(0.5f * pp[0], &s0, &c0);
        sincosf(0.5f * pp[1], &s1, &c1);
        sincosf(0.5f * pp[2], &s2, &c2);
        float2 U[4], M[4];
        if (l < NLAYERS) {
            // U = Rz(p2) * Ry(p1) * Rx(p0)
            float2 RX[4] = { {c0, 0.f}, {0.f, -s0}, {0.f, -s0}, {c0, 0.f} };
            float2 RY[4] = { {c1, 0.f}, {-s1, 0.f}, {s1, 0.f}, {c1, 0.f} };
            float2 RZ[4] = { {c2, -s2}, {0.f, 0.f}, {0.f, 0.f}, {c2, s2} };
            mat2mul(RY, RX, M);
            mat2mul(RZ, M, U);
        } else {
            // U = Ry(p2) * Rz(p1) * Ry(p0)
            float2 RY0[4] = { {c0, 0.f}, {-s0, 0.f}, {s0, 0.f}, {c0, 0.f} };
            float2 RZ1[4] = { {c1, -s1}, {0.f, 0.f}, {0.f, 0.f}, {c1, s1} };
            float2 RY2[4] = { {c2, 0.f}, {-s2, 0.f}, {s2, 0.f}, {c2, 0.f} };
            mat2mul(RZ1, RY0, M);
            mat2mul(RY2, M, U);
        }
        gmat[tid * 4 + 0] = (v2f){U[0].x, U[0].y};
        gmat[tid * 4 + 1] = (v2f){U[1].x, U[1].y};
        gmat[tid * 4 + 2] = (v2f){U[2].x, U[2].y};
        gmat[tid * 4 + 3] = (v2f){U[3].x, U[3].y};
    }

    // ---- load x in C layout (i = 16*tid + j), compute sum of squares ----
    const float* xb = x + (size_t)b * DIM;
    v2f r[16];
    float ss = 0.f;
    {
        const float4* xv = reinterpret_cast<const float4*>(xb + 16 * tid);
        #pragma unroll
        for (int k = 0; k < 4; ++k) {
            float4 v = xv[k];
            r[k * 4 + 0] = (v2f){v.x, 0.f};
            r[k * 4 + 1] = (v2f){v.y, 0.f};
            r[k * 4 + 2] = (v2f){v.z, 0.f};
            r[k * 4 + 3] = (v2f){v.w, 0.f};
            ss += v.x * v.x + v.y * v.y + v.z * v.z + v.w * v.w;
        }
    }
    #pragma unroll
    for (int off = 32; off > 0; off >>= 1) ss += __shfl_down(ss, off, 64);
    if ((tid & 63) == 0) red[tid >> 6] = ss;
    __syncthreads();   // covers gmat + red

    const float total = red[0] + red[1] + red[2] + red[3];
    const float inv = 1.0f / sqrtf(sqrtf(total) + 1e-12f);
    #pragma unroll
    for (int j = 0; j < 16; ++j) { r[j].x *= inv; }

    // per-thread layout constants
    const int cxor = (tid & 7) << 1;                     // C-layout slot xor
    const int bbase = (tid >> 4) << 8;                   // B-layout base
    const int tl = tid & 15;                             // B-layout low bits
    const int tA = tid ^ (((tid >> 4) & 7) << 1);        // A-layout slot low byte

    // ---- circuit ----
    for (int l = 0; l < NLAYERS + 1; ++l) {
        const int goff = 12 * l;

        // phase C: bits 0-3 (qubits 11..8)
        apply_phase<0>(r, gmat, goff);

        // transpose C -> B
        #pragma unroll
        for (int j = 0; j < 16; j += 2) {
            *reinterpret_cast<v4f*>(&st[16 * tid + (j ^ cxor)]) =
                (v4f){r[j].x, r[j].y, r[j + 1].x, r[j + 1].y};
        }
        __syncthreads();
        #pragma unroll
        for (int j = 0; j < 16; ++j) {
            r[j] = st[bbase | (j << 4) | (tl ^ ((j & 7) << 1))];
        }
        __syncthreads();

        // phase B: bits 4-7 (qubits 7..4)
        apply_phase<4>(r, gmat, goff);

        // transpose B -> A
        #pragma unroll
        for (int j = 0; j < 16; ++j) {
            st[bbase | (j << 4) | (tl ^ ((j & 7) << 1))] = r[j];
        }
        __syncthreads();
        #pragma unroll
        for (int j = 0; j < 16; ++j) {
            r[j] = st[(j << 8) | tA];
        }
        __syncthreads();

        // phase A: bits 8-11 (qubits 3..0)
        apply_phase<8>(r, gmat, goff);

        if (l == NLAYERS) break;   // final layer: no ring of CNOTs

        // ring-of-CNOT permutation fused into transpose A -> C:
        // new[i] = old[y(i)], y = i ^ (i>>1) ^ ((i&1)*0xC00)
        #pragma unroll
        for (int j = 0; j < 16; ++j) {
            st[(j << 8) | tA] = r[j];
        }
        __syncthreads();
        #pragma unroll
        for (int j = 0; j < 16; ++j) {
            const int i = 16 * tid + j;
            int y = i ^ (i >> 1);
            y ^= (i & 1) * 0xC00;
            r[j] = st[y ^ ((y >> 3) & 14)];
        }
        __syncthreads();
    }

    // ---- store real part from A layout: i = (j<<8) | tid -> coalesced ----
    float* ob = out + (size_t)b * DIM;
    #pragma unroll
    for (int j = 0; j < 16; ++j) {
        ob[(j << 8) | tid] = r[j].x;
    }
}

extern "C" void kernel_launch(void* const* d_in, const int* in_sizes, int n_in,
                              void* d_out, int out_size, void* d_ws, size_t ws_size,
                              hipStream_t stream) {
    const float* x = (const float*)d_in[0];      // [1024, 4096] f32
    const float* w = (const float*)d_in[1];      // [216] f32
    float* out = (float*)d_out;                  // [1024, 4096] f32
    qsim_kernel<<<dim3(1024), dim3(TPB), 0, stream>>>(x, w, out);
}